// Round 4
// baseline (684.451 us; speedup 1.0000x reference)
//
#include <hip/hip_runtime.h>

#define HH 512
#define WWID 512
#define CIN 64
#define COUT 64
#define TH 8
#define TW 32

typedef float fx4 __attribute__((ext_vector_type(4)));  // native vec for NT store

// 1/sqrt(#valid positions in {y-1,y,y+1} within [0,n))
__device__ __forceinline__ float edge_rsqrt(int y, int n) {
  int r = 1 + (y > 0 ? 1 : 0) + (y < n - 1 ? 1 : 0);
  return __frsqrt_rn((float)r);
}

__global__ __launch_bounds__(256, 3)
void gcn_fused(const float* __restrict__ x, const float* __restrict__ wgt,
               float* __restrict__ out) {
  // double-buffered per-phase t-tiles: 8 channels x 256 pixels per buffer (16 KB)
  __shared__ __align__(16) float ts[2][8][TH * TW];

  const int t  = threadIdx.x;
  const int g  = t & 63;                                   // pixel group 0..63
  const int og = __builtin_amdgcn_readfirstlane(t >> 6);   // wave id 0..3 (uniform)
  const int b  = blockIdx.z;
  const int h0 = blockIdx.y * TH;
  const int w0 = blockIdx.x * TW;
  const int row = g >> 3;          // 0..7
  const int cg  = g & 7;           // 0..7 column group (4 pixels each)
  const int h = h0 + row;
  const int w = w0 + cg * 4;

  // row factors (dinv row component) for rows h-1..h+1; 0 if out of image
  float srh[3]; int hi[3];
#pragma unroll
  for (int i = 0; i < 3; ++i) {
    int y = h - 1 + i;
    bool v = (y >= 0) && (y < HH);
    srh[i] = v ? edge_rsqrt(y, HH) : 0.0f;
    hi[i] = v ? y : h;  // clamped (factor 0 kills the value)
  }
  // column factors for cols w-1..w+4
  float srw[6];
#pragma unroll
  for (int j = 0; j < 6; ++j) {
    int xw = w - 1 + j;
    bool v = (xw >= 0) && (xw < WWID);
    srw[j] = v ? edge_rsqrt(xw, WWID) : 0.0f;
  }
  const int wl = (w > 0) ? (w - 1) : w;                // clamped left col
  const int wr = (w + 4 < WWID) ? (w + 4) : w;         // clamped right col

  float4 acc[16];
#pragma unroll
  for (int j = 0; j < 16; ++j) acc[j] = make_float4(0.f, 0.f, 0.f, 0.f);

  const size_t plane = (size_t)HH * WWID;
  const float* xb = x + (size_t)b * CIN * plane;

  // prologue: prefetch phase-0 channels (og*2, og*2+1)
  float lv[2][3], rv[2][3]; float4 mv[2][3];
#pragma unroll
  for (int k = 0; k < 2; ++k) {
    const float* xp = xb + (size_t)(og * 2 + k) * plane;
#pragma unroll
    for (int i = 0; i < 3; ++i) {
      const float* rp = xp + (size_t)hi[i] * WWID;
      lv[k][i] = rp[wl];
      mv[k][i] = *(const float4*)(rp + w);
      rv[k][i] = rp[wr];
    }
  }

  for (int p = 0; p < 8; ++p) {
    // stencil: vertical combine (6 cols) then horizontal windows (4 outs).
    // t_k = sum_j srw[k+j'] * vs[k+j'], vs_j = sum_i srh[i]*v[i][j]
#pragma unroll
    for (int k = 0; k < 2; ++k) {
      float vs0 = lv[k][0]   * srh[0] + lv[k][1]   * srh[1] + lv[k][2]   * srh[2];
      float vs1 = mv[k][0].x * srh[0] + mv[k][1].x * srh[1] + mv[k][2].x * srh[2];
      float vs2 = mv[k][0].y * srh[0] + mv[k][1].y * srh[1] + mv[k][2].y * srh[2];
      float vs3 = mv[k][0].z * srh[0] + mv[k][1].z * srh[1] + mv[k][2].z * srh[2];
      float vs4 = mv[k][0].w * srh[0] + mv[k][1].w * srh[1] + mv[k][2].w * srh[2];
      float vs5 = rv[k][0]   * srh[0] + rv[k][1]   * srh[1] + rv[k][2]   * srh[2];
      float t0 = srw[0] * vs0 + srw[1] * vs1 + srw[2] * vs2;
      float t1 = srw[1] * vs1 + srw[2] * vs2 + srw[3] * vs3;
      float t2 = srw[2] * vs2 + srw[3] * vs3 + srw[4] * vs4;
      float t3 = srw[3] * vs3 + srw[4] * vs4 + srw[5] * vs5;
      *(float4*)&ts[p & 1][og * 2 + k][4 * g] = make_float4(t0, t1, t2, t3);
    }
    // single barrier per phase: buf p&1 now ready; previous phase's readers
    // used buf (p-1)&1, and re-writes of this buf (phase p+2) sit behind the
    // next barrier, so one barrier suffices.
    __syncthreads();

    // prefetch next phase's x rows; latency hidden under the 512-FMA GEMM
    if (p < 7) {
#pragma unroll
      for (int k = 0; k < 2; ++k) {
        const float* xp = xb + (size_t)((p + 1) * 8 + og * 2 + k) * plane;
#pragma unroll
        for (int i = 0; i < 3; ++i) {
          const float* rp = xp + (size_t)hi[i] * WWID;
          lv[k][i] = rp[wl];
          mv[k][i] = *(const float4*)(rp + w);
          rv[k][i] = rp[wr];
        }
      }
    }

    // GEMM: 8 channels x 16 output cols; W via uniform (scalar) loads
#pragma unroll
    for (int cc = 0; cc < 8; ++cc) {
      float4 tv = *(const float4*)&ts[p & 1][cc][4 * g];
      const float* wp = wgt + (size_t)(p * 8 + cc) * COUT + og * 16;
#pragma unroll
      for (int j = 0; j < 16; ++j) {
        float wj = wp[j];
        acc[j].x += tv.x * wj;
        acc[j].y += tv.y * wj;
        acc[j].z += tv.z * wj;
        acc[j].w += tv.w * wj;
      }
    }
  }

  // epilogue: apply outer dinv, store [b][o][h][w]; NT stores keep the
  // write-once output out of L2/L3 so input halo re-reads can hit cache
  const float dp0 = srh[1] * srw[1];
  const float dp1 = srh[1] * srw[2];
  const float dp2 = srh[1] * srw[3];
  const float dp3 = srh[1] * srw[4];
  float* ob = out + (size_t)b * COUT * plane + (size_t)h * WWID + w;
#pragma unroll
  for (int j = 0; j < 16; ++j) {
    fx4 r;
    r.x = acc[j].x * dp0;
    r.y = acc[j].y * dp1;
    r.z = acc[j].z * dp2;
    r.w = acc[j].w * dp3;
    __builtin_nontemporal_store(r, (fx4*)(ob + (size_t)(og * 16 + j) * plane));
  }
}

extern "C" void kernel_launch(void* const* d_in, const int* in_sizes, int n_in,
                              void* d_out, int out_size, void* d_ws, size_t ws_size,
                              hipStream_t stream) {
  const float* x = (const float*)d_in[0];
  const float* wgt = (const float*)d_in[1];
  float* out = (float*)d_out;
  dim3 grid(WWID / TW, HH / TH, 4);  // 16 x 64 x 4 = 4096 blocks
  gcn_fused<<<grid, dim3(256), 0, stream>>>(x, wgt, out);
}